// Round 5
// baseline (131.888 us; speedup 1.0000x reference)
//
#include <hip/hip_runtime.h>

// GNN_51539607552576 — round 5.
// Phase 1 (proj): occupancy-first rewrite. 1 thread = 1 pixel (scalar loads),
//   block = 256 thr = 4 channel-slices x 64 px, 17 KB LDS reduce,
//   __launch_bounds__(256,8) -> VGPR<=64 -> 32 waves/CU. 2048 blocks.
// Phase 2 (gnn_node): unchanged from round 4 (per-output-node split, ~10 us).

namespace {
constexpr int S     = 128 * 128;
constexpr int BATCH = 4;
constexpr int HID   = 10;
constexpr int INDIM = 256;
constexpr int NPIX  = BATCH * S;   // 65536

struct Ptrs {
  const float* __restrict__ xp;
  const float* __restrict__ xh;
  const float* __restrict__ xf;
  const float* __restrict__ p_fea;
  const float* __restrict__ h_fea;
  const float* __restrict__ Wf_comp;  const float* __restrict__ bf_comp;
  const float* __restrict__ Wf_uatt;  const float* __restrict__ bf_uatt;
  const float* __restrict__ Wf_uupd;
  const float* __restrict__ Wh_pdp_f; const float* __restrict__ Wh_pdp_x;
  const float* __restrict__ bh_pdp;
  const float* __restrict__ Wh_att;   const float* __restrict__ bh_att;
  const float* __restrict__ Wh_cu;    const float* __restrict__ bh_cu;
  const float* __restrict__ Wh_cl;    const float* __restrict__ bh_cl;
  const float* __restrict__ Wh_dec_f; const float* __restrict__ Wh_dec_x;
  const float* __restrict__ bh_dec;
  const float* __restrict__ Wh_uatt;  const float* __restrict__ bh_uatt;
  const float* __restrict__ Wh_uupd;
  const float* __restrict__ Wp_pdp_f; const float* __restrict__ Wp_pdp_x;
  const float* __restrict__ bp_pdp;
  const float* __restrict__ Wp_att;   const float* __restrict__ bp_att;
  const float* __restrict__ Wp_dec_f; const float* __restrict__ Wp_dec_x;
  const float* __restrict__ bp_dec;
  const float* __restrict__ Wp_uatt;  const float* __restrict__ bp_uatt;
  const float* __restrict__ Wp_uupd;
  float* __restrict__ out;
  float* __restrict__ ws;
};

__device__ __forceinline__ float sigmoidf(float x) {
  return 1.0f / (1.0f + __expf(-x));
}

// ============================ Phase 1: projections ============================
// ws rows: 0..9 fh, 10..11 hdec, 12..21 fpj, 22..27 pdec. Column = pixel id.
// Block: 256 thr = 4 slices (64 ch each) x 64 px; thread = 1 px, scalar loads.
// Grid: (NPIX/64, 2 streams) = 2048 blocks -> 8 blocks/CU -> 32 waves/CU.

constexpr int LPAD = 17;   // row stride (floats), odd -> conflict-free

template <int NO>  // 12 (h stream) or 16 (p stream)
__device__ __forceinline__ void proj_impl(
    float* lds,                           // [4*64][LPAD]
    const float* __restrict__ fea,
    const float* __restrict__ Wa,         // [10][INDIM]
    const float* __restrict__ Wb,         // [NO-10][INDIM]
    float* __restrict__ ws, int obase) {
  const int t  = threadIdx.x;
  const int px = t & 63;
  const int sl = __builtin_amdgcn_readfirstlane(t >> 6);  // wave-uniform slice
  const int pb = blockIdx.x * 64;          // block pixel base
  const int b  = pb >> 14;
  const int p  = (pb & (S - 1)) + px;

  float acc[NO];
#pragma unroll
  for (int o = 0; o < NO; ++o) acc[o] = 0.f;

  const float* __restrict__ base = fea + (size_t)(b * INDIM + sl * 64) * S + p;

  // 8-deep scalar prefetch pipeline over 64 channels (8 batches of 8)
  float cur[8];
#pragma unroll
  for (int i = 0; i < 8; ++i) cur[i] = base[(size_t)i * S];

#pragma unroll
  for (int blk = 0; blk < 8; ++blk) {
    float nxt[8];
    if (blk < 7) {
#pragma unroll
      for (int i = 0; i < 8; ++i)
        nxt[i] = base[(size_t)((blk + 1) * 8 + i) * S];
    }
#pragma unroll
    for (int i = 0; i < 8; ++i) {
      const int c = sl * 64 + blk * 8 + i;   // wave-uniform -> s_load weights
      const float v = cur[i];
#pragma unroll
      for (int o = 0; o < 10; ++o)
        acc[o] = fmaf(v, Wa[o * INDIM + c], acc[o]);
#pragma unroll
      for (int o = 10; o < NO; ++o)
        acc[o] = fmaf(v, Wb[(o - 10) * INDIM + c], acc[o]);
    }
    if (blk < 7) {
#pragma unroll
      for (int i = 0; i < 8; ++i) cur[i] = nxt[i];
    }
  }

  // stage partials: row (sl*64+px)
  float* row = lds + (sl * 64 + px) * LPAD;
#pragma unroll
  for (int o = 0; o < NO; ++o) row[o] = acc[o];
  __syncthreads();

  // reduce 4 slices: 256 thr = 64 px x 4 output-groups of K outputs
  constexpr int K = NO / 4;
  const int og = t >> 6;
#pragma unroll
  for (int k = 0; k < K; ++k) {
    const int o = og * K + k;
    const float s = lds[(0 * 64 + px) * LPAD + o] +
                    lds[(1 * 64 + px) * LPAD + o] +
                    lds[(2 * 64 + px) * LPAD + o] +
                    lds[(3 * 64 + px) * LPAD + o];
    ws[(size_t)(obase + o) * NPIX + pb + px] = s;
  }
}

__global__ __launch_bounds__(256, 8) void proj_kernel(Ptrs P) {
  __shared__ float lds[4 * 64 * LPAD];   // 17.4 KB -> 8 blocks/CU fits 160 KB
  if (blockIdx.y == 0) {
    proj_impl<12>(lds, P.h_fea, P.Wh_pdp_f, P.Wh_dec_f, P.ws, 0);
  } else {
    proj_impl<16>(lds, P.p_fea, P.Wp_pdp_f, P.Wp_dec_f, P.ws, 12);
  }
}

// ============================ Phase 2: per-node graph math ============================

__device__ __forceinline__ void att_update_store(
    const float* x, const float* m,
    const float* __restrict__ Wa, float ba, const float* __restrict__ Wu,
    float* __restrict__ outp) {
  float a = ba;
#pragma unroll
  for (int c = 0; c < HID; ++c) a = fmaf(x[c], Wa[c], a);
#pragma unroll
  for (int c = 0; c < HID; ++c) a = fmaf(m[c], Wa[HID + c], a);
  a = sigmoidf(a);
#pragma unroll
  for (int o = 0; o < HID; ++o) {
    float u = 0.f;
#pragma unroll
    for (int c = 0; c < HID; ++c) u = fmaf(x[c], Wu[o * 2 * HID + c], u);
#pragma unroll
    for (int c = 0; c < HID; ++c) u = fmaf(m[c], Wu[o * 2 * HID + HID + c], u);
    u = fmaxf(u, 0.f);
    outp[(size_t)o * S] = x[o] * (1.f - a) + u * a;
  }
}

__device__ __forceinline__ void load10(float* dst, const float* __restrict__ src,
                                       int plane, int p) {
#pragma unroll
  for (int c = 0; c < HID; ++c)
    dst[c] = src[((size_t)plane * HID + c) * S + p];
}

// grid.y = node id: 0..5 parts, 6..7 halves, 8 full
__global__ __launch_bounds__(256) void gnn_node(Ptrs P) {
  const int tid = blockIdx.x * blockDim.x + threadIdx.x;
  const int b = tid >> 14;
  const int p = tid & (S - 1);
  const int y = blockIdx.y;

  if (y == 8) {
    // ---------------- full graph ----------------
    float xh0[HID], xh1[HID], xfv[HID];
    load10(xh0, P.xh, 0 * BATCH + b, p);
    load10(xh1, P.xh, 1 * BATCH + b, p);
    load10(xfv, P.xf, b, p);
    float a0 = P.bf_comp[0], a1 = P.bf_comp[1];
#pragma unroll
    for (int c = 0; c < HID; ++c) {
      a0 = fmaf(xh0[c], P.Wf_comp[c], a0);
      a1 = fmaf(xh1[c], P.Wf_comp[HID + c], a1);
    }
    a0 = sigmoidf(a0); a1 = sigmoidf(a1);
    float msg[HID];
#pragma unroll
    for (int c = 0; c < HID; ++c) msg[c] = a0 * xh0[c] + a1 * xh1[c];
    att_update_store(xfv, msg, P.Wf_uatt, P.bf_uatt[0], P.Wf_uupd,
                     P.out + ((size_t)(8 * BATCH + b) * HID) * S + p);
  } else if (y >= 6) {
    // ---------------- half graph, node h ----------------
    const int h = y - 6;
    float xh_self[HID], xh_oth[HID], xfv[HID], fh[HID];
    load10(xh_self, P.xh, h * BATCH + b, p);
    load10(xh_oth,  P.xh, (1 - h) * BATCH + b, p);
    load10(xfv, P.xf, b, p);
#pragma unroll
    for (int o = 0; o < HID; ++o) fh[o] = P.ws[(size_t)o * NPIX + tid];
    const float hdec = P.ws[(size_t)(10 + h) * NPIX + tid];

    const int nsrc = h ? 2 : 4;
    const int sbase = h ? 4 : 0;
    const float* __restrict__ Wc = h ? P.Wh_cl : P.Wh_cu;
    const float* __restrict__ bc = h ? P.bh_cl : P.bh_cu;
    float comp[HID];
#pragma unroll
    for (int o = 0; o < HID; ++o) comp[o] = 0.f;
#pragma unroll
    for (int i = 0; i < 4; ++i) {
      if (i < nsrc) {
        float xpi[HID];
        load10(xpi, P.xp, (sbase + i) * BATCH + b, p);
        float s = bc[i];
#pragma unroll
        for (int c = 0; c < HID; ++c) s = fmaf(xpi[c], Wc[i * HID + c], s);
        s = sigmoidf(s);
#pragma unroll
        for (int c = 0; c < HID; ++c) comp[c] = fmaf(s, xpi[c], comp[c]);
      }
    }

    float a_self = P.bh_att[h], a_oth = P.bh_att[1 - h];
#pragma unroll
    for (int c = 0; c < HID; ++c) {
      a_self = fmaf(xh_self[c], P.Wh_att[h * HID + c], a_self);
      a_oth  = fmaf(xh_oth[c],  P.Wh_att[(1 - h) * HID + c], a_oth);
    }
    a_self = sigmoidf(a_self); a_oth = sigmoidf(a_oth);
    const float wg = a_oth * (1.f - a_self);

    float d = hdec + P.bh_dec[h];
#pragma unroll
    for (int c = 0; c < HID; ++c) d = fmaf(xh_self[c], P.Wh_dec_x[h * HID + c], d);
    d = sigmoidf(d);

    float m[HID];
#pragma unroll
    for (int o = 0; o < HID; ++o) {
      float dp = fh[o] + P.bh_pdp[o];
#pragma unroll
      for (int c = 0; c < HID; ++c) dp = fmaf(xh_oth[c], P.Wh_pdp_x[o * HID + c], dp);
      dp = fmaxf(dp, 0.f);
      m[o] = comp[o] + dp * wg + d * xfv[o];
    }
    att_update_store(xh_self, m, P.Wh_uatt + h * 2 * HID, P.bh_uatt[h],
                     P.Wh_uupd + h * HID * 2 * HID,
                     P.out + ((size_t)((6 + h) * BATCH + b) * HID) * S + p);
  } else {
    // ---------------- part graph, node n ----------------
    const int n = y;
    const int half = (n < 4) ? 0 : 1;
    // ADJ columns: dst0{1} dst1{0,2,3,4,5} dst2{1} dst3{1} dst4{1,5} dst5{1,4}
    const unsigned masks[6] = {0x02u, 0x3Du, 0x02u, 0x02u, 0x22u, 0x12u};
    const unsigned mask = masks[n];

    float xpn[HID], xh_s[HID], fpj[HID];
    load10(xpn, P.xp, n * BATCH + b, p);
    load10(xh_s, P.xh, half * BATCH + b, p);
#pragma unroll
    for (int o = 0; o < HID; ++o) fpj[o] = P.ws[(size_t)(12 + o) * NPIX + tid];
    const float pdecn = P.ws[(size_t)(22 + n) * NPIX + tid];

    float pattn = P.bp_att[n];
#pragma unroll
    for (int c = 0; c < HID; ++c) pattn = fmaf(xpn[c], P.Wp_att[n * HID + c], pattn);
    pattn = sigmoidf(pattn);

    float msum[HID];
#pragma unroll
    for (int o = 0; o < HID; ++o) msum[o] = 0.f;
#pragma unroll
    for (int src = 0; src < 6; ++src) {
      if (mask & (1u << src)) {
        float xps[HID];
        load10(xps, P.xp, src * BATCH + b, p);
        float ps = P.bp_att[src];
#pragma unroll
        for (int c = 0; c < HID; ++c) ps = fmaf(xps[c], P.Wp_att[src * HID + c], ps);
        ps = sigmoidf(ps);
#pragma unroll
        for (int o = 0; o < HID; ++o) {
          float dp = fpj[o] + P.bp_pdp[o];
#pragma unroll
          for (int c = 0; c < HID; ++c) dp = fmaf(xps[c], P.Wp_pdp_x[o * HID + c], dp);
          msum[o] = fmaf(fmaxf(dp, 0.f), ps, msum[o]);
        }
      }
    }

    float dg = pdecn + P.bp_dec[n];
#pragma unroll
    for (int c = 0; c < HID; ++c) dg = fmaf(xpn[c], P.Wp_dec_x[n * HID + c], dg);
    dg = sigmoidf(dg);

    const float onem = 1.f - pattn;
    float m[HID];
#pragma unroll
    for (int o = 0; o < HID; ++o) m[o] = onem * msum[o] + dg * xh_s[o];

    att_update_store(xpn, m, P.Wp_uatt + n * 2 * HID, P.bp_uatt[n],
                     P.Wp_uupd + n * HID * 2 * HID,
                     P.out + ((size_t)(n * BATCH + b) * HID) * S + p);
  }
}

}  // namespace

extern "C" void kernel_launch(void* const* d_in, const int* in_sizes, int n_in,
                              void* d_out, int out_size, void* d_ws, size_t ws_size,
                              hipStream_t stream) {
  Ptrs P;
  P.xp       = (const float*)d_in[0];
  P.xh       = (const float*)d_in[1];
  P.xf       = (const float*)d_in[2];
  // d_in[3] = bg_node (unused)
  P.p_fea    = (const float*)d_in[4];
  P.h_fea    = (const float*)d_in[5];
  // d_in[6] = f_fea (unused)
  P.Wf_comp  = (const float*)d_in[7];
  P.bf_comp  = (const float*)d_in[8];
  P.Wf_uatt  = (const float*)d_in[9];
  P.bf_uatt  = (const float*)d_in[10];
  P.Wf_uupd  = (const float*)d_in[11];
  P.Wh_pdp_f = (const float*)d_in[12];
  P.Wh_pdp_x = (const float*)d_in[13];
  P.bh_pdp   = (const float*)d_in[14];
  P.Wh_att   = (const float*)d_in[15];
  P.bh_att   = (const float*)d_in[16];
  P.Wh_cu    = (const float*)d_in[17];
  P.bh_cu    = (const float*)d_in[18];
  P.Wh_cl    = (const float*)d_in[19];
  P.bh_cl    = (const float*)d_in[20];
  P.Wh_dec_f = (const float*)d_in[21];
  P.Wh_dec_x = (const float*)d_in[22];
  P.bh_dec   = (const float*)d_in[23];
  P.Wh_uatt  = (const float*)d_in[24];
  P.bh_uatt  = (const float*)d_in[25];
  P.Wh_uupd  = (const float*)d_in[26];
  P.Wp_pdp_f = (const float*)d_in[27];
  P.Wp_pdp_x = (const float*)d_in[28];
  P.bp_pdp   = (const float*)d_in[29];
  P.Wp_att   = (const float*)d_in[30];
  P.bp_att   = (const float*)d_in[31];
  P.Wp_dec_f = (const float*)d_in[32];
  P.Wp_dec_x = (const float*)d_in[33];
  P.bp_dec   = (const float*)d_in[34];
  P.Wp_uatt  = (const float*)d_in[35];
  P.bp_uatt  = (const float*)d_in[36];
  P.Wp_uupd  = (const float*)d_in[37];
  P.out      = (float*)d_out;
  P.ws       = (float*)d_ws;   // 28 * 65536 * 4 = 7.34 MB

  // Phase 1: 1024 pixel-blocks (64 px each) x 2 streams = 2048 blocks
  proj_kernel<<<dim3(NPIX / 64, 2), dim3(256), 0, stream>>>(P);
  // Phase 2: 256 pixel-blocks x 9 output nodes
  gnn_node<<<dim3(NPIX / 256, 9), dim3(256), 0, stream>>>(P);
}

// Round 6
// 67.951 us; speedup vs baseline: 1.9409x; 1.9409x over previous
//
#include <hip/hip_runtime.h>

// GNN_51539607552576 — round 6.
// Phase 1 (proj): R4 geometry (float4 pixels, 256 px/block, 4 slice-waves x 64ch,
//   512 blocks) + 16-deep ROLLING RING prefetch (consume-then-refill, static
//   indices) so the compiler emits counted vmcnt waits instead of draining to
//   vmcnt(0) every 8 channels. launch_bounds(256,2) -> 256 VGPR budget.
// Phase 2 (gnn_node): unchanged (per-output-node split, ~10 us).

namespace {
constexpr int S     = 128 * 128;
constexpr int BATCH = 4;
constexpr int HID   = 10;
constexpr int INDIM = 256;
constexpr int NPIX  = BATCH * S;   // 65536

struct Ptrs {
  const float* __restrict__ xp;
  const float* __restrict__ xh;
  const float* __restrict__ xf;
  const float* __restrict__ p_fea;
  const float* __restrict__ h_fea;
  const float* __restrict__ Wf_comp;  const float* __restrict__ bf_comp;
  const float* __restrict__ Wf_uatt;  const float* __restrict__ bf_uatt;
  const float* __restrict__ Wf_uupd;
  const float* __restrict__ Wh_pdp_f; const float* __restrict__ Wh_pdp_x;
  const float* __restrict__ bh_pdp;
  const float* __restrict__ Wh_att;   const float* __restrict__ bh_att;
  const float* __restrict__ Wh_cu;    const float* __restrict__ bh_cu;
  const float* __restrict__ Wh_cl;    const float* __restrict__ bh_cl;
  const float* __restrict__ Wh_dec_f; const float* __restrict__ Wh_dec_x;
  const float* __restrict__ bh_dec;
  const float* __restrict__ Wh_uatt;  const float* __restrict__ bh_uatt;
  const float* __restrict__ Wh_uupd;
  const float* __restrict__ Wp_pdp_f; const float* __restrict__ Wp_pdp_x;
  const float* __restrict__ bp_pdp;
  const float* __restrict__ Wp_att;   const float* __restrict__ bp_att;
  const float* __restrict__ Wp_dec_f; const float* __restrict__ Wp_dec_x;
  const float* __restrict__ bp_dec;
  const float* __restrict__ Wp_uatt;  const float* __restrict__ bp_uatt;
  const float* __restrict__ Wp_uupd;
  float* __restrict__ out;
  float* __restrict__ ws;
};

__device__ __forceinline__ float sigmoidf(float x) {
  return 1.0f / (1.0f + __expf(-x));
}

// ============================ Phase 1: projections ============================
// ws rows: 0..9 fh, 10..11 hdec, 12..21 fpj, 22..27 pdec. Column = pixel id.
// Block: 256 thr = 64 px-groups (x4 px, float4) x 4 slice-waves (64 ch each).
// Grid: (NPIX/256, 2 streams) = 512 blocks = 2/CU = 8 waves/CU (grid-capped),
// so VGPR budget is 256/wave -> 16-deep float4 ring fits without spills.

constexpr int LROW = 65;   // LDS row stride (floats); 65 mod 32 = 1 -> conflict-free
constexpr int RD   = 16;   // ring depth (channels in flight per wave)

template <int NO>  // 12 (h stream) or 16 (p stream)
__device__ __forceinline__ void proj_impl(
    float* lds,                           // [256][LROW]
    const float* __restrict__ fea,
    const float* __restrict__ Wa,         // [10][INDIM]
    const float* __restrict__ Wb,         // [NO-10][INDIM]
    float* __restrict__ ws, int obase) {
  const int t   = threadIdx.x;
  const int pxg = t & 63;
  const int sl  = __builtin_amdgcn_readfirstlane(t >> 6);  // wave-uniform slice
  const int pb  = blockIdx.x * 256;        // block pixel base
  const int b   = pb >> 14;
  const int p0  = pb & (S - 1);
  const size_t S4 = S / 4;

  float4 acc[NO];
#pragma unroll
  for (int o = 0; o < NO; ++o) acc[o] = float4{0.f, 0.f, 0.f, 0.f};

  const float4* __restrict__ base =
      (const float4*)(fea + (size_t)(b * INDIM + sl * 64) * S + p0) + pxg;

  // ---- rolling ring: RD channels in flight, consume-then-refill ----
  float4 ring[RD];
#pragma unroll
  for (int i = 0; i < RD; ++i) ring[i] = base[(size_t)i * S4];

#pragma unroll 1
  for (int cb = 0; cb < 64 - RD; cb += RD) {   // cb = 0, 16, 32
#pragma unroll
    for (int i = 0; i < RD; ++i) {
      const float4 v = ring[i];                 // waits only this slot's load
      ring[i] = base[(size_t)(cb + RD + i) * S4];  // refill: keeps RD in flight
      const int c = sl * 64 + cb + i;           // wave-uniform channel
#pragma unroll
      for (int o = 0; o < 10; ++o) {
        const float w = Wa[o * INDIM + c];
        acc[o].x = fmaf(v.x, w, acc[o].x);
        acc[o].y = fmaf(v.y, w, acc[o].y);
        acc[o].z = fmaf(v.z, w, acc[o].z);
        acc[o].w = fmaf(v.w, w, acc[o].w);
      }
#pragma unroll
      for (int o = 10; o < NO; ++o) {
        const float w = Wb[(o - 10) * INDIM + c];
        acc[o].x = fmaf(v.x, w, acc[o].x);
        acc[o].y = fmaf(v.y, w, acc[o].y);
        acc[o].z = fmaf(v.z, w, acc[o].z);
        acc[o].w = fmaf(v.w, w, acc[o].w);
      }
    }
  }
  // epilogue: consume last RD channels, no refill
#pragma unroll
  for (int i = 0; i < RD; ++i) {
    const float4 v = ring[i];
    const int c = sl * 64 + (64 - RD) + i;
#pragma unroll
    for (int o = 0; o < 10; ++o) {
      const float w = Wa[o * INDIM + c];
      acc[o].x = fmaf(v.x, w, acc[o].x);
      acc[o].y = fmaf(v.y, w, acc[o].y);
      acc[o].z = fmaf(v.z, w, acc[o].z);
      acc[o].w = fmaf(v.w, w, acc[o].w);
    }
#pragma unroll
    for (int o = 10; o < NO; ++o) {
      const float w = Wb[(o - 10) * INDIM + c];
      acc[o].x = fmaf(v.x, w, acc[o].x);
      acc[o].y = fmaf(v.y, w, acc[o].y);
      acc[o].z = fmaf(v.z, w, acc[o].z);
      acc[o].w = fmaf(v.w, w, acc[o].w);
    }
  }

  // stage partials: row = sl*64 + pxg (stride-65 rows -> conflict-free)
  float* row = lds + (sl * 64 + pxg) * LROW;
#pragma unroll
  for (int o = 0; o < NO; ++o) {
    row[4 * o + 0] = acc[o].x;
    row[4 * o + 1] = acc[o].y;
    row[4 * o + 2] = acc[o].z;
    row[4 * o + 3] = acc[o].w;
  }
  __syncthreads();

  // reduce 4 slices: 256 thr = 64 pxg x 4 output-groups of K outputs
  constexpr int K = NO / 4;
  const int og = t >> 6;
#pragma unroll
  for (int k = 0; k < K; ++k) {
    const int o = og * K + k;
    float r[4] = {0.f, 0.f, 0.f, 0.f};
#pragma unroll
    for (int s2 = 0; s2 < 4; ++s2) {
      const float* rr = lds + (s2 * 64 + pxg) * LROW + 4 * o;
#pragma unroll
      for (int j = 0; j < 4; ++j) r[j] += rr[j];
    }
    float4 res; res.x = r[0]; res.y = r[1]; res.z = r[2]; res.w = r[3];
    *(float4*)(ws + (size_t)(obase + o) * NPIX + pb + pxg * 4) = res;
  }
}

__global__ __launch_bounds__(256, 2) void proj_kernel(Ptrs P) {
  __shared__ float lds[256 * LROW];   // 66.6 KB -> 2 blocks/CU (133 KB < 160)
  if (blockIdx.y == 0) {
    proj_impl<12>(lds, P.h_fea, P.Wh_pdp_f, P.Wh_dec_f, P.ws, 0);
  } else {
    proj_impl<16>(lds, P.p_fea, P.Wp_pdp_f, P.Wp_dec_f, P.ws, 12);
  }
}

// ============================ Phase 2: per-node graph math ============================

__device__ __forceinline__ void att_update_store(
    const float* x, const float* m,
    const float* __restrict__ Wa, float ba, const float* __restrict__ Wu,
    float* __restrict__ outp) {
  float a = ba;
#pragma unroll
  for (int c = 0; c < HID; ++c) a = fmaf(x[c], Wa[c], a);
#pragma unroll
  for (int c = 0; c < HID; ++c) a = fmaf(m[c], Wa[HID + c], a);
  a = sigmoidf(a);
#pragma unroll
  for (int o = 0; o < HID; ++o) {
    float u = 0.f;
#pragma unroll
    for (int c = 0; c < HID; ++c) u = fmaf(x[c], Wu[o * 2 * HID + c], u);
#pragma unroll
    for (int c = 0; c < HID; ++c) u = fmaf(m[c], Wu[o * 2 * HID + HID + c], u);
    u = fmaxf(u, 0.f);
    outp[(size_t)o * S] = x[o] * (1.f - a) + u * a;
  }
}

__device__ __forceinline__ void load10(float* dst, const float* __restrict__ src,
                                       int plane, int p) {
#pragma unroll
  for (int c = 0; c < HID; ++c)
    dst[c] = src[((size_t)plane * HID + c) * S + p];
}

// grid.y = node id: 0..5 parts, 6..7 halves, 8 full
__global__ __launch_bounds__(256) void gnn_node(Ptrs P) {
  const int tid = blockIdx.x * blockDim.x + threadIdx.x;
  const int b = tid >> 14;
  const int p = tid & (S - 1);
  const int y = blockIdx.y;

  if (y == 8) {
    // ---------------- full graph ----------------
    float xh0[HID], xh1[HID], xfv[HID];
    load10(xh0, P.xh, 0 * BATCH + b, p);
    load10(xh1, P.xh, 1 * BATCH + b, p);
    load10(xfv, P.xf, b, p);
    float a0 = P.bf_comp[0], a1 = P.bf_comp[1];
#pragma unroll
    for (int c = 0; c < HID; ++c) {
      a0 = fmaf(xh0[c], P.Wf_comp[c], a0);
      a1 = fmaf(xh1[c], P.Wf_comp[HID + c], a1);
    }
    a0 = sigmoidf(a0); a1 = sigmoidf(a1);
    float msg[HID];
#pragma unroll
    for (int c = 0; c < HID; ++c) msg[c] = a0 * xh0[c] + a1 * xh1[c];
    att_update_store(xfv, msg, P.Wf_uatt, P.bf_uatt[0], P.Wf_uupd,
                     P.out + ((size_t)(8 * BATCH + b) * HID) * S + p);
  } else if (y >= 6) {
    // ---------------- half graph, node h ----------------
    const int h = y - 6;
    float xh_self[HID], xh_oth[HID], xfv[HID], fh[HID];
    load10(xh_self, P.xh, h * BATCH + b, p);
    load10(xh_oth,  P.xh, (1 - h) * BATCH + b, p);
    load10(xfv, P.xf, b, p);
#pragma unroll
    for (int o = 0; o < HID; ++o) fh[o] = P.ws[(size_t)o * NPIX + tid];
    const float hdec = P.ws[(size_t)(10 + h) * NPIX + tid];

    const int nsrc = h ? 2 : 4;
    const int sbase = h ? 4 : 0;
    const float* __restrict__ Wc = h ? P.Wh_cl : P.Wh_cu;
    const float* __restrict__ bc = h ? P.bh_cl : P.bh_cu;
    float comp[HID];
#pragma unroll
    for (int o = 0; o < HID; ++o) comp[o] = 0.f;
#pragma unroll
    for (int i = 0; i < 4; ++i) {
      if (i < nsrc) {
        float xpi[HID];
        load10(xpi, P.xp, (sbase + i) * BATCH + b, p);
        float s = bc[i];
#pragma unroll
        for (int c = 0; c < HID; ++c) s = fmaf(xpi[c], Wc[i * HID + c], s);
        s = sigmoidf(s);
#pragma unroll
        for (int c = 0; c < HID; ++c) comp[c] = fmaf(s, xpi[c], comp[c]);
      }
    }

    float a_self = P.bh_att[h], a_oth = P.bh_att[1 - h];
#pragma unroll
    for (int c = 0; c < HID; ++c) {
      a_self = fmaf(xh_self[c], P.Wh_att[h * HID + c], a_self);
      a_oth  = fmaf(xh_oth[c],  P.Wh_att[(1 - h) * HID + c], a_oth);
    }
    a_self = sigmoidf(a_self); a_oth = sigmoidf(a_oth);
    const float wg = a_oth * (1.f - a_self);

    float d = hdec + P.bh_dec[h];
#pragma unroll
    for (int c = 0; c < HID; ++c) d = fmaf(xh_self[c], P.Wh_dec_x[h * HID + c], d);
    d = sigmoidf(d);

    float m[HID];
#pragma unroll
    for (int o = 0; o < HID; ++o) {
      float dp = fh[o] + P.bh_pdp[o];
#pragma unroll
      for (int c = 0; c < HID; ++c) dp = fmaf(xh_oth[c], P.Wh_pdp_x[o * HID + c], dp);
      dp = fmaxf(dp, 0.f);
      m[o] = comp[o] + dp * wg + d * xfv[o];
    }
    att_update_store(xh_self, m, P.Wh_uatt + h * 2 * HID, P.bh_uatt[h],
                     P.Wh_uupd + h * HID * 2 * HID,
                     P.out + ((size_t)((6 + h) * BATCH + b) * HID) * S + p);
  } else {
    // ---------------- part graph, node n ----------------
    const int n = y;
    const int half = (n < 4) ? 0 : 1;
    // ADJ columns: dst0{1} dst1{0,2,3,4,5} dst2{1} dst3{1} dst4{1,5} dst5{1,4}
    const unsigned masks[6] = {0x02u, 0x3Du, 0x02u, 0x02u, 0x22u, 0x12u};
    const unsigned mask = masks[n];

    float xpn[HID], xh_s[HID], fpj[HID];
    load10(xpn, P.xp, n * BATCH + b, p);
    load10(xh_s, P.xh, half * BATCH + b, p);
#pragma unroll
    for (int o = 0; o < HID; ++o) fpj[o] = P.ws[(size_t)(12 + o) * NPIX + tid];
    const float pdecn = P.ws[(size_t)(22 + n) * NPIX + tid];

    float pattn = P.bp_att[n];
#pragma unroll
    for (int c = 0; c < HID; ++c) pattn = fmaf(xpn[c], P.Wp_att[n * HID + c], pattn);
    pattn = sigmoidf(pattn);

    float msum[HID];
#pragma unroll
    for (int o = 0; o < HID; ++o) msum[o] = 0.f;
#pragma unroll
    for (int src = 0; src < 6; ++src) {
      if (mask & (1u << src)) {
        float xps[HID];
        load10(xps, P.xp, src * BATCH + b, p);
        float ps = P.bp_att[src];
#pragma unroll
        for (int c = 0; c < HID; ++c) ps = fmaf(xps[c], P.Wp_att[src * HID + c], ps);
        ps = sigmoidf(ps);
#pragma unroll
        for (int o = 0; o < HID; ++o) {
          float dp = fpj[o] + P.bp_pdp[o];
#pragma unroll
          for (int c = 0; c < HID; ++c) dp = fmaf(xps[c], P.Wp_pdp_x[o * HID + c], dp);
          msum[o] = fmaf(fmaxf(dp, 0.f), ps, msum[o]);
        }
      }
    }

    float dg = pdecn + P.bp_dec[n];
#pragma unroll
    for (int c = 0; c < HID; ++c) dg = fmaf(xpn[c], P.Wp_dec_x[n * HID + c], dg);
    dg = sigmoidf(dg);

    const float onem = 1.f - pattn;
    float m[HID];
#pragma unroll
    for (int o = 0; o < HID; ++o) m[o] = onem * msum[o] + dg * xh_s[o];

    att_update_store(xpn, m, P.Wp_uatt + n * 2 * HID, P.bp_uatt[n],
                     P.Wp_uupd + n * HID * 2 * HID,
                     P.out + ((size_t)(n * BATCH + b) * HID) * S + p);
  }
}

}  // namespace

extern "C" void kernel_launch(void* const* d_in, const int* in_sizes, int n_in,
                              void* d_out, int out_size, void* d_ws, size_t ws_size,
                              hipStream_t stream) {
  Ptrs P;
  P.xp       = (const float*)d_in[0];
  P.xh       = (const float*)d_in[1];
  P.xf       = (const float*)d_in[2];
  // d_in[3] = bg_node (unused)
  P.p_fea    = (const float*)d_in[4];
  P.h_fea    = (const float*)d_in[5];
  // d_in[6] = f_fea (unused)
  P.Wf_comp  = (const float*)d_in[7];
  P.bf_comp  = (const float*)d_in[8];
  P.Wf_uatt  = (const float*)d_in[9];
  P.bf_uatt  = (const float*)d_in[10];
  P.Wf_uupd  = (const float*)d_in[11];
  P.Wh_pdp_f = (const float*)d_in[12];
  P.Wh_pdp_x = (const float*)d_in[13];
  P.bh_pdp   = (const float*)d_in[14];
  P.Wh_att   = (const float*)d_in[15];
  P.bh_att   = (const float*)d_in[16];
  P.Wh_cu    = (const float*)d_in[17];
  P.bh_cu    = (const float*)d_in[18];
  P.Wh_cl    = (const float*)d_in[19];
  P.bh_cl    = (const float*)d_in[20];
  P.Wh_dec_f = (const float*)d_in[21];
  P.Wh_dec_x = (const float*)d_in[22];
  P.bh_dec   = (const float*)d_in[23];
  P.Wh_uatt  = (const float*)d_in[24];
  P.bh_uatt  = (const float*)d_in[25];
  P.Wh_uupd  = (const float*)d_in[26];
  P.Wp_pdp_f = (const float*)d_in[27];
  P.Wp_pdp_x = (const float*)d_in[28];
  P.bp_pdp   = (const float*)d_in[29];
  P.Wp_att   = (const float*)d_in[30];
  P.bp_att   = (const float*)d_in[31];
  P.Wp_dec_f = (const float*)d_in[32];
  P.Wp_dec_x = (const float*)d_in[33];
  P.bp_dec   = (const float*)d_in[34];
  P.Wp_uatt  = (const float*)d_in[35];
  P.bp_uatt  = (const float*)d_in[36];
  P.Wp_uupd  = (const float*)d_in[37];
  P.out      = (float*)d_out;
  P.ws       = (float*)d_ws;   // 28 * 65536 * 4 = 7.34 MB

  // Phase 1: 256 pixel-blocks x 2 streams = 512 blocks, 256 px per block
  proj_kernel<<<dim3(NPIX / 256, 2), dim3(256), 0, stream>>>(P);
  // Phase 2: 256 pixel-blocks x 9 output nodes
  gnn_node<<<dim3(NPIX / 256, 9), dim3(256), 0, stream>>>(P);
}